// Round 4
// baseline (326.352 us; speedup 1.0000x reference)
//
#include <hip/hip_runtime.h>
#include <hip/hip_bf16.h>

typedef __attribute__((ext_vector_type(8))) short bf16x8;
typedef __attribute__((ext_vector_type(4))) float f32x4;

#define PBAR()  asm volatile("s_barrier" ::: "memory")
#define LGKM0() asm volatile("s_waitcnt lgkmcnt(0)" ::: "memory")
#define VMC(n)  asm volatile("s_waitcnt vmcnt(" #n ")" ::: "memory")

__device__ __forceinline__ uint pack_bf16x2(float a, float b) {
    __hip_bfloat162 p = __float22bfloat162_rn(make_float2(a, b));
    union { __hip_bfloat162 h; uint u; } c; c.h = p; return c.u;
}
__device__ __forceinline__ float bfu(ushort u) { return __uint_as_float(((uint)u) << 16); }

__device__ __forceinline__ float fast_tanh(float x) {
    float e = __expf(2.f * x);
    return 1.f - 2.f * __builtin_amdgcn_rcpf(e + 1.f);
}

__device__ __forceinline__ float wredmax(float v) {
    #pragma unroll
    for (int o = 32; o; o >>= 1) v = fmaxf(v, __shfl_xor(v, o, 64));
    return v;
}
__device__ __forceinline__ float wredsum(float v) {
    #pragma unroll
    for (int o = 32; o; o >>= 1) v += __shfl_xor(v, o, 64);
    return v;
}

__device__ __forceinline__ void gload16(const void* g, void* l) {
    __builtin_amdgcn_global_load_lds(
        (const __attribute__((address_space(1))) void*)g,
        (__attribute__((address_space(3))) void*)l, 16, 0, 0);
}

// ---------------- batched f32 -> bf16 conversion ----------------
struct CvtTab {
    const float* src[16];
    ushort* dst[16];
    unsigned cum[17];
};

__global__ void cvt_all(CvtTab t, unsigned total4) {
    unsigned stride = gridDim.x * blockDim.x;
    for (unsigned i = blockIdx.x * blockDim.x + threadIdx.x; i < total4; i += stride) {
        int j = 0;
        while (i >= t.cum[j + 1]) ++j;
        unsigned off = i - t.cum[j];
        float4 v = reinterpret_cast<const float4*>(t.src[j])[off];
        uint2 o;
        o.x = pack_bf16x2(v.x, v.y);
        o.y = pack_bf16x2(v.z, v.w);
        reinterpret_cast<uint2*>(t.dst[j])[off] = o;
    }
}

// ============ 8-phase counted-vmcnt score GEMM: 512 thr, 256x256 tile, dbuf 128KB ============
// K-major LDS: A at [buf][ks][16KB], W at +65536 same. Half-tile = one K-half of A or W
// (256 rows x 32 cols, 2 gload_lds/thread). Per tile (4 phases):
//   L1: rd(k0 B+A[0-3]); stage A-k1,W-k1 of t+1;            bar; lgkm; 16 MFMA; bar
//   L2: rd(k0 A[4-7]);                                      bar; lgkm; 16 MFMA; bar
//   L3: rd(k1 B+A[0-3]); stage A-k0 of t+2;                 bar; lgkm; 16 MFMA; bar
//   L4: rd(k1 A[4-7]);   stage W-k0 of t+2; vmcnt(4);       bar; lgkm; 16 MFMA; bar
// Race-safety: every stage targeting buffer region R issues >=1 barrier after the last
// ds_read of R's previous generation (k0 regions read only at L1/L2; k1 only at L3/L4).
struct PArgs {
    const ushort* A[2];
    const ushort* Wa[2];
    const ushort* Wb[2];
    const float* qa[2];
    const float* qb[2];
    const float* va[2];
    const float* vb[2];
    float* oa[2];
    float* ob[2];
};

__global__ __launch_bounds__(512, 1) void gemm_pipe(PArgs P, int nmul, int nbadd,
                                                    int bshift, int brshift)
{
    extern __shared__ char smem[];

    const int tid = threadIdx.x;
    const int lane = tid & 63, wv = tid >> 6;
    const int wr = wv >> 2, wc = wv & 3;
    const int lrow = lane & 15, lk = lane >> 4;

    const int br = blockIdx.x >> brshift;
    const int m0 = (blockIdx.x & ((1 << brshift) - 1)) << 8;
    const int na = blockIdx.y * nmul;
    const int nb = na + nbadd;

    const ushort* A  = P.A[br];
    const ushort* Wa = P.Wa[br];
    const ushort* Wb = P.Wb[br];

    // ---- staging source mapping (inverse of the paired-unit chunk swizzle) ----
    // LDS within-half byte L = j*8192 + tid*16; u=L/128, pos=(L%128)/16;
    // (rowpar<<2|chunk) = pos ^ (u&7); row = u*2+rowpar.
    const int xsw  = (tid & 7) ^ ((tid >> 3) & 7);
    const int row0 = ((tid >> 3) << 1) + (xsw >> 2);   // 0..127 (j adds 128)
    const int chnk = xsw & 3;
    const ushort* sA0 = A  + (size_t)(m0 + row0) * 1024 + chnk * 8;
    const ushort* sA1 = sA0 + (size_t)128 * 1024;
    const ushort* sWa = Wa + (size_t)(na + row0) * 1024 + chnk * 8;
    const ushort* sWb = Wb + (size_t)(nb + row0) * 1024 + chnk * 8;
    const int sdst = tid * 16;

    auto stgA = [&](int t, int ks) {
        char* d = smem + (t & 1) * 32768 + ks * 16384 + sdst;
        int off = t * 64 + ks * 32;
        gload16(sA0 + off, d);
        gload16(sA1 + off, d + 8192);
    };
    auto stgW = [&](int t, int ks) {
        char* d = smem + 65536 + (t & 1) * 32768 + ks * 16384 + sdst;
        int off = t * 64 + ks * 32;
        gload16(sWa + off, d);
        gload16(sWb + off, d + 8192);
    };

    // ---- fragment reads: pos = ((lrow&1)<<2 | lk) ^ (lrow>>1), per-lane constant ----
    const int posC = ((((lrow & 1) << 2) | lk) ^ (lrow >> 1)) << 4;
    const int rbA = wr * 8192 + (lrow >> 1) * 128 + posC;   // + mi*1024
    const int rbB = wc * 4096 + (lrow >> 1) * 128 + posC;   // + ni*1024

    auto rdA = [&](int bs, int ks, int mi) -> bf16x8 {
        return *(const bf16x8*)(smem + bs * 32768 + ks * 16384 + mi * 1024 + rbA);
    };
    auto rdB = [&](int bs, int ks, int ni) -> bf16x8 {
        return *(const bf16x8*)(smem + 65536 + bs * 32768 + ks * 16384 + ni * 1024 + rbB);
    };

    f32x4 acc[8][4];
    #pragma unroll
    for (int i = 0; i < 8; ++i)
        #pragma unroll
        for (int j = 0; j < 4; ++j) { f32x4 z = {0.f,0.f,0.f,0.f}; acc[i][j] = z; }

    // ---- prologue: tile0 all 4 halves + tile1 k0 halves; allow tile1's 4 loads in flight
    stgA(0, 0); stgW(0, 0); stgA(0, 1); stgW(0, 1);
    stgA(1, 0); stgW(1, 0);
    VMC(4);
    PBAR();

    bf16x8 af[4], bfr[4];
    #pragma unroll 1
    for (int t = 0; t < 16; ++t) {
        const int bs = t & 1;
        // ---- L1: ks0, mi 0-3 ----
        #pragma unroll
        for (int ni = 0; ni < 4; ++ni) bfr[ni] = rdB(bs, 0, ni);
        #pragma unroll
        for (int mi = 0; mi < 4; ++mi) af[mi] = rdA(bs, 0, mi);
        if (t < 15) { stgA(t + 1, 1); stgW(t + 1, 1); }
        else { VMC(0); }
        PBAR(); LGKM0();
        __builtin_amdgcn_s_setprio(1);
        #pragma unroll
        for (int mi = 0; mi < 4; ++mi)
            #pragma unroll
            for (int ni = 0; ni < 4; ++ni)
                acc[mi][ni] = __builtin_amdgcn_mfma_f32_16x16x32_bf16(af[mi], bfr[ni], acc[mi][ni], 0, 0, 0);
        __builtin_amdgcn_s_setprio(0);
        PBAR();
        // ---- L2: ks0, mi 4-7 ----
        #pragma unroll
        for (int mi = 0; mi < 4; ++mi) af[mi] = rdA(bs, 0, mi + 4);
        PBAR(); LGKM0();
        __builtin_amdgcn_s_setprio(1);
        #pragma unroll
        for (int mi = 0; mi < 4; ++mi)
            #pragma unroll
            for (int ni = 0; ni < 4; ++ni)
                acc[mi + 4][ni] = __builtin_amdgcn_mfma_f32_16x16x32_bf16(af[mi], bfr[ni], acc[mi + 4][ni], 0, 0, 0);
        __builtin_amdgcn_s_setprio(0);
        PBAR();
        // ---- L3: ks1, mi 0-3 ----
        #pragma unroll
        for (int ni = 0; ni < 4; ++ni) bfr[ni] = rdB(bs, 1, ni);
        #pragma unroll
        for (int mi = 0; mi < 4; ++mi) af[mi] = rdA(bs, 1, mi);
        if (t < 14) stgA(t + 2, 0);
        PBAR(); LGKM0();
        __builtin_amdgcn_s_setprio(1);
        #pragma unroll
        for (int mi = 0; mi < 4; ++mi)
            #pragma unroll
            for (int ni = 0; ni < 4; ++ni)
                acc[mi][ni] = __builtin_amdgcn_mfma_f32_16x16x32_bf16(af[mi], bfr[ni], acc[mi][ni], 0, 0, 0);
        __builtin_amdgcn_s_setprio(0);
        PBAR();
        // ---- L4: ks1, mi 4-7 ----
        #pragma unroll
        for (int mi = 0; mi < 4; ++mi) af[mi] = rdA(bs, 1, mi + 4);
        if (t < 14) stgW(t + 2, 0);
        VMC(4);
        PBAR(); LGKM0();
        __builtin_amdgcn_s_setprio(1);
        #pragma unroll
        for (int mi = 0; mi < 4; ++mi)
            #pragma unroll
            for (int ni = 0; ni < 4; ++ni)
                acc[mi + 4][ni] = __builtin_amdgcn_mfma_f32_16x16x32_bf16(af[mi], bfr[ni], acc[mi + 4][ni], 0, 0, 0);
        __builtin_amdgcn_s_setprio(0);
        PBAR();
    }

    // ---- score epilogue (per-wave side: wc<2 -> a, else -> b) ----
    const float* qsrc = (wc < 2) ? P.qa[br] : P.qb[br];
    const float* vsrc = (wc < 2) ? P.va[br] : P.vb[br];
    float* osrc       = (wc < 2) ? P.oa[br] : P.ob[br];
    const int nbase0 = ((wc < 2) ? na : nb) + (wc & 1) * 64;
    #pragma unroll
    for (int mi = 0; mi < 8; ++mi) {
        int mbase = m0 + wr * 128 + mi * 16;
        int bb = mbase >> bshift;
        const float* qrow = qsrc + (size_t)bb * 1024;
        float part[4] = {0.f, 0.f, 0.f, 0.f};
        #pragma unroll
        for (int ni = 0; ni < 4; ++ni) {
            int nn = nbase0 + ni * 16 + lrow;
            float qn = qrow[nn], vn = vsrc[nn];
            #pragma unroll
            for (int r = 0; r < 4; ++r)
                part[r] += fast_tanh(acc[mi][ni][r] + qn) * vn;
        }
        #pragma unroll
        for (int off = 1; off < 16; off <<= 1)
            #pragma unroll
            for (int r = 0; r < 4; ++r)
                part[r] += __shfl_xor(part[r], off, 64);
        if (lrow == 0) {
            #pragma unroll
            for (int r = 0; r < 4; ++r)
                atomicAdd(&osrc[mbase + lk * 4 + r], part[r]);
        }
    }
}

// ============ fused 4-way q-projection: q = x @ W^T + b  (M=128, single-buffered) ============
struct QArgs {
    const ushort* A[4];
    const ushort* W[4];
    const float* bias[4];
    float* out[4];
};

__global__ __launch_bounds__(256, 2) void gemm_q(QArgs Q)
{
    __shared__ char smemq[32768];
    char* As = smemq;
    char* Ws = smemq + 16384;

    const int tid = threadIdx.x;
    const int lane = tid & 63, wv = tid >> 6, wr = wv >> 1, wc = wv & 1;
    const int lrow = lane & 15, lk = lane >> 4;
    const int n0 = blockIdx.y << 7;

    const ushort* A = Q.A[blockIdx.x];
    const ushort* W = Q.W[blockIdx.x];

    f32x4 acc[4][4];
    #pragma unroll
    for (int i = 0; i < 4; ++i)
        #pragma unroll
        for (int j = 0; j < 4; ++j) { f32x4 z = {0.f,0.f,0.f,0.f}; acc[i][j] = z; }

    const int srow = tid >> 3;
    const int g = (tid & 7) ^ (srow & 7);
    const ushort* pA = A + (size_t)srow * 1024 + g * 8;
    const ushort* pW = W + (size_t)(n0 + srow) * 1024 + g * 8;

    for (int t = 0; t < 16; ++t) {
        #pragma unroll
        for (int j = 0; j < 4; ++j)
            gload16(pA + (size_t)j * 32768 + (size_t)t * 64, As + j * 4096 + tid * 16);
        #pragma unroll
        for (int j = 0; j < 4; ++j)
            gload16(pW + (size_t)j * 32768 + (size_t)t * 64, Ws + j * 4096 + tid * 16);
        __syncthreads();
        #pragma unroll
        for (int ks = 0; ks < 2; ++ks) {
            bf16x8 af[4], bfr[4];
            const int q = ks * 4 + lk;
            #pragma unroll
            for (int mi = 0; mi < 4; ++mi) {
                int row = wr * 64 + mi * 16 + lrow;
                af[mi] = *(const bf16x8*)(As + row * 128 + ((q ^ (row & 7)) << 4));
            }
            #pragma unroll
            for (int ni = 0; ni < 4; ++ni) {
                int row = wc * 64 + ni * 16 + lrow;
                bfr[ni] = *(const bf16x8*)(Ws + row * 128 + ((q ^ (row & 7)) << 4));
            }
            #pragma unroll
            for (int mi = 0; mi < 4; ++mi)
                #pragma unroll
                for (int ni = 0; ni < 4; ++ni)
                    acc[mi][ni] = __builtin_amdgcn_mfma_f32_16x16x32_bf16(af[mi], bfr[ni], acc[mi][ni], 0, 0, 0);
        }
        __syncthreads();
    }

    float* out = Q.out[blockIdx.x];
    const float* bias = Q.bias[blockIdx.x];
    #pragma unroll
    for (int mi = 0; mi < 4; ++mi) {
        int mrow0 = wr * 64 + mi * 16 + lk * 4;
        #pragma unroll
        for (int ni = 0; ni < 4; ++ni) {
            int n = n0 + wc * 64 + ni * 16 + lrow;
            float bv = bias[n];
            #pragma unroll
            for (int r = 0; r < 4; ++r)
                out[(size_t)(mrow0 + r) * 1024 + n] = acc[mi][ni][r] + bv;
        }
    }
}

// ============ final GEMM (split-K, atomic): out += combined @ W_out^T (+bias at z==0) ============
__global__ __launch_bounds__(256, 2) void gemm_fin(
    const ushort* A, const ushort* W, const float* bias, float* out, int K, int kchunk)
{
    __shared__ char smemf[32768];
    char* As = smemf;
    char* Ws = smemf + 16384;

    const int tid = threadIdx.x;
    const int lane = tid & 63, wv = tid >> 6, wr = wv >> 1, wc = wv & 1;
    const int lrow = lane & 15, lk = lane >> 4;
    const int n0 = blockIdx.y << 7;
    const int nkt = kchunk >> 6;
    const int ktbase = blockIdx.z * nkt;

    f32x4 acc[4][4];
    #pragma unroll
    for (int i = 0; i < 4; ++i)
        #pragma unroll
        for (int j = 0; j < 4; ++j) { f32x4 z = {0.f,0.f,0.f,0.f}; acc[i][j] = z; }

    const int srow = tid >> 3;
    const int g = (tid & 7) ^ (srow & 7);
    const ushort* pA = A + (size_t)srow * K + ktbase * 64 + g * 8;
    const ushort* pW = W + (size_t)(n0 + srow) * K + ktbase * 64 + g * 8;

    for (int t = 0; t < nkt; ++t) {
        #pragma unroll
        for (int j = 0; j < 4; ++j)
            gload16(pA + (size_t)j * 32 * K + (size_t)t * 64, As + j * 4096 + tid * 16);
        #pragma unroll
        for (int j = 0; j < 4; ++j)
            gload16(pW + (size_t)j * 32 * K + (size_t)t * 64, Ws + j * 4096 + tid * 16);
        __syncthreads();
        #pragma unroll
        for (int ks = 0; ks < 2; ++ks) {
            bf16x8 af[4], bfr[4];
            const int q = ks * 4 + lk;
            #pragma unroll
            for (int mi = 0; mi < 4; ++mi) {
                int row = wr * 64 + mi * 16 + lrow;
                af[mi] = *(const bf16x8*)(As + row * 128 + ((q ^ (row & 7)) << 4));
            }
            #pragma unroll
            for (int ni = 0; ni < 4; ++ni) {
                int row = wc * 64 + ni * 16 + lrow;
                bfr[ni] = *(const bf16x8*)(Ws + row * 128 + ((q ^ (row & 7)) << 4));
            }
            #pragma unroll
            for (int mi = 0; mi < 4; ++mi)
                #pragma unroll
                for (int ni = 0; ni < 4; ++ni)
                    acc[mi][ni] = __builtin_amdgcn_mfma_f32_16x16x32_bf16(af[mi], bfr[ni], acc[mi][ni], 0, 0, 0);
        }
        __syncthreads();
    }

    #pragma unroll
    for (int mi = 0; mi < 4; ++mi) {
        int mrow0 = wr * 64 + mi * 16 + lk * 4;
        #pragma unroll
        for (int ni = 0; ni < 4; ++ni) {
            int n = n0 + wc * 64 + ni * 16 + lrow;
            float bv = (blockIdx.z == 0) ? bias[n] : 0.f;
            #pragma unroll
            for (int r = 0; r < 4; ++r)
                atomicAdd(&out[(size_t)(mrow0 + r) * 1024 + n], acc[mi][ni][r] + bv);
        }
    }
}

// ---------------- softmax + context, image branches ----------------
__global__ void softmax_ctx_img(const ushort* __restrict__ iof, const ushort* __restrict__ ipf,
                                const float* __restrict__ sc_io, const float* __restrict__ sc_ip,
                                ushort* __restrict__ combined)
{
    int b = blockIdx.x, br = blockIdx.y;
    const ushort* A  = br ? ipf : iof;
    const float* sc  = br ? sc_ip : sc_io;
    __shared__ float dist[64];
    int tid = threadIdx.x;
    if (tid < 64) {
        float s  = sc[b * 64 + tid];
        float mx = wredmax(s);
        float e  = __expf(s - mx);
        float sm = wredsum(e);
        dist[tid] = e / sm;
    }
    __syncthreads();
    int d0 = tid * 4;
    float a0 = 0, a1 = 0, a2 = 0, a3 = 0;
    const ushort* base = A + (size_t)b * 64 * 1024 + d0;
    #pragma unroll 4
    for (int n = 0; n < 64; ++n) {
        float w = dist[n];
        ushort4 t = *(const ushort4*)(base + (size_t)n * 1024);
        a0 += w * bfu(t.x); a1 += w * bfu(t.y); a2 += w * bfu(t.z); a3 += w * bfu(t.w);
    }
    uint2 o;
    o.x = pack_bf16x2(a0, a1);
    o.y = pack_bf16x2(a2, a3);
    *(uint2*)(combined + (size_t)b * 4096 + br * 1024 + d0) = o;
}

// ---------------- masked softmax + context, text branches ----------------
__global__ void softmax_ctx_text(const ushort* __restrict__ tf,
                                 const float* __restrict__ sc_to, const float* __restrict__ sc_tp,
                                 const float* __restrict__ mask, ushort* __restrict__ combined)
{
    int b = blockIdx.x;
    __shared__ float d3[256], d4[256], red[8];
    int tid = threadIdx.x, lane = tid & 63, wv = tid >> 6;
    float s3 = sc_to[b * 256 + tid], s4 = sc_tp[b * 256 + tid], m = mask[b * 256 + tid];
    float m3 = wredmax(s3), m4 = wredmax(s4);
    if (lane == 0) { red[wv] = m3; red[4 + wv] = m4; }
    __syncthreads();
    m3 = fmaxf(fmaxf(red[0], red[1]), fmaxf(red[2], red[3]));
    m4 = fmaxf(fmaxf(red[4], red[5]), fmaxf(red[6], red[7]));
    float e3 = __expf(s3 - m3) * m, e4 = __expf(s4 - m4) * m;
    float t3 = wredsum(e3), t4 = wredsum(e4);
    __syncthreads();
    if (lane == 0) { red[wv] = t3; red[4 + wv] = t4; }
    __syncthreads();
    t3 = red[0] + red[1] + red[2] + red[3];
    t4 = red[4] + red[5] + red[6] + red[7];
    d3[tid] = e3 / t3; d4[tid] = e4 / t4;
    __syncthreads();
    int d0 = tid * 4;
    float a0 = 0, a1 = 0, a2 = 0, a3 = 0, c0 = 0, c1 = 0, c2 = 0, c3 = 0;
    const ushort* base = tf + (size_t)b * 256 * 1024 + d0;
    #pragma unroll 4
    for (int l = 0; l < 256; ++l) {
        float w3 = d3[l], w4 = d4[l];
        ushort4 t = *(const ushort4*)(base + (size_t)l * 1024);
        float f0 = bfu(t.x), f1 = bfu(t.y), f2 = bfu(t.z), f3 = bfu(t.w);
        a0 += w3 * f0; a1 += w3 * f1; a2 += w3 * f2; a3 += w3 * f3;
        c0 += w4 * f0; c1 += w4 * f1; c2 += w4 * f2; c3 += w4 * f3;
    }
    uint2 o;
    o.x = pack_bf16x2(a0, a1); o.y = pack_bf16x2(a2, a3);
    *(uint2*)(combined + (size_t)b * 4096 + 2048 + d0) = o;
    o.x = pack_bf16x2(c0, c1); o.y = pack_bf16x2(c2, c3);
    *(uint2*)(combined + (size_t)b * 4096 + 3072 + d0) = o;
}

extern "C" void kernel_launch(void* const* d_in, const int* in_sizes, int n_in,
                              void* d_out, int out_size, void* d_ws, size_t ws_size,
                              hipStream_t stream) {
    const float* text_feat        = (const float*)d_in[0];
    const float* text_feats       = (const float*)d_in[1];
    const float* img_object_feat  = (const float*)d_in[2];
    const float* img_object_feats = (const float*)d_in[3];
    const float* img_place_feat   = (const float*)d_in[4];
    const float* img_place_feats  = (const float*)d_in[5];
    const float* src_mask         = (const float*)d_in[6];
    const float* v_to  = (const float*)d_in[7];
    const float* v_tp  = (const float*)d_in[8];
    const float* v_io  = (const float*)d_in[9];
    const float* v_ip  = (const float*)d_in[10];
    const float* Wsrc[9] = {
        (const float*)d_in[11],  // W_t2o
        (const float*)d_in[12],  // W_t2p
        (const float*)d_in[13],  // W_o2t
        (const float*)d_in[14],  // W_p2t
        (const float*)d_in[15],  // W_oo
        (const float*)d_in[17],  // W_pp
        (const float*)d_in[19],  // W_tot
        (const float*)d_in[21],  // W_tpt
        (const float*)d_in[23],  // W_out
    };
    const float* b_oo  = (const float*)d_in[16];
    const float* b_pp  = (const float*)d_in[18];
    const float* b_tot = (const float*)d_in[20];
    const float* b_tpt = (const float*)d_in[22];
    const float* b_out = (const float*)d_in[24];

    // ---- workspace layout ----
    char* p = (char*)d_ws;
    auto alloc = [&](size_t bytes) { char* r = p; p += (bytes + 255) & ~(size_t)255; return r; };
    ushort* wb[9];
    for (int i = 0; i < 8; ++i) wb[i] = (ushort*)alloc((size_t)1024 * 1024 * 2);
    wb[8] = (ushort*)alloc((size_t)1024 * 4096 * 2);
    ushort* tf_bf   = (ushort*)alloc((size_t)32768 * 1024 * 2);
    ushort* iof_bf  = (ushort*)alloc((size_t)8192 * 1024 * 2);
    ushort* ipf_bf  = (ushort*)alloc((size_t)8192 * 1024 * 2);
    ushort* tfq_bf  = (ushort*)alloc((size_t)128 * 1024 * 2);
    ushort* iofq_bf = (ushort*)alloc((size_t)128 * 1024 * 2);
    ushort* ipfq_bf = (ushort*)alloc((size_t)128 * 1024 * 2);
    float* q_tot = (float*)alloc((size_t)128 * 1024 * 4);
    float* q_tpt = (float*)alloc((size_t)128 * 1024 * 4);
    float* q_oo  = (float*)alloc((size_t)128 * 1024 * 4);
    float* q_pp  = (float*)alloc((size_t)128 * 1024 * 4);
    float* scores = (float*)alloc((size_t)(8192 * 2 + 32768 * 2) * 4);
    float* sc_io = scores, *sc_ip = scores + 8192, *sc_to = scores + 16384, *sc_tp = scores + 49152;
    ushort* comb_bf = (ushort*)alloc((size_t)128 * 4096 * 2);

    // ---- 1) batched f32->bf16 conversion ----
    CvtTab tab;
    unsigned n4[15];
    const float* srcs[15];
    ushort* dsts[15];
    for (int i = 0; i < 8; ++i) { srcs[i] = Wsrc[i]; dsts[i] = wb[i]; n4[i] = 262144; }
    srcs[8]  = Wsrc[8];          dsts[8]  = wb[8];   n4[8]  = 1048576;
    srcs[9]  = text_feats;       dsts[9]  = tf_bf;   n4[9]  = 8388608;
    srcs[10] = img_object_feats; dsts[10] = iof_bf;  n4[10] = 2097152;
    srcs[11] = img_place_feats;  dsts[11] = ipf_bf;  n4[11] = 2097152;
    srcs[12] = text_feat;        dsts[12] = tfq_bf;  n4[12] = 32768;
    srcs[13] = img_object_feat;  dsts[13] = iofq_bf; n4[13] = 32768;
    srcs[14] = img_place_feat;   dsts[14] = ipfq_bf; n4[14] = 32768;
    unsigned cum = 0;
    for (int i = 0; i < 15; ++i) {
        tab.src[i] = srcs[i]; tab.dst[i] = dsts[i]; tab.cum[i] = cum; cum += n4[i];
    }
    tab.src[15] = nullptr; tab.dst[15] = nullptr; tab.cum[15] = cum; tab.cum[16] = cum;
    cvt_all<<<4096, 256, 0, stream>>>(tab, cum);

    // ---- 2) zero atomic targets ----
    hipMemsetAsync(scores, 0, (size_t)(8192 * 2 + 32768 * 2) * 4, stream);
    hipMemsetAsync(d_out, 0, (size_t)128 * 1024 * 4, stream);

    // ---- 3) fused q projections ----
    QArgs qa;
    qa.A[0] = tfq_bf;  qa.W[0] = wb[6]; qa.bias[0] = b_tot; qa.out[0] = q_tot;
    qa.A[1] = tfq_bf;  qa.W[1] = wb[7]; qa.bias[1] = b_tpt; qa.out[1] = q_tpt;
    qa.A[2] = iofq_bf; qa.W[2] = wb[4]; qa.bias[2] = b_oo;  qa.out[2] = q_oo;
    qa.A[3] = ipfq_bf; qa.W[3] = wb[5]; qa.bias[3] = b_pp;  qa.out[3] = q_pp;
    gemm_q<<<dim3(4, 8), 256, 0, stream>>>(qa);

    // ---- 4) score GEMMs (8-phase pipelined) ----
    PArgs pi;
    pi.A[0] = iof_bf;  pi.Wa[0] = wb[2]; pi.Wb[0] = wb[2];
    pi.qa[0] = q_tot;  pi.qb[0] = q_tot; pi.va[0] = v_to; pi.vb[0] = v_to;
    pi.oa[0] = sc_io;  pi.ob[0] = sc_io;
    pi.A[1] = ipf_bf;  pi.Wa[1] = wb[3]; pi.Wb[1] = wb[3];
    pi.qa[1] = q_tpt;  pi.qb[1] = q_tpt; pi.va[1] = v_tp; pi.vb[1] = v_tp;
    pi.oa[1] = sc_ip;  pi.ob[1] = sc_ip;
    gemm_pipe<<<dim3(64, 4), 512, 131072, stream>>>(pi, 256, 128, 6, 5);

    PArgs pt;
    pt.A[0] = tf_bf;   pt.Wa[0] = wb[0]; pt.Wb[0] = wb[1];
    pt.qa[0] = q_oo;   pt.qb[0] = q_pp;  pt.va[0] = v_io; pt.vb[0] = v_ip;
    pt.oa[0] = sc_to;  pt.ob[0] = sc_tp;
    pt.A[1] = pt.A[0]; pt.Wa[1] = pt.Wa[0]; pt.Wb[1] = pt.Wb[0];
    pt.qa[1] = pt.qa[0]; pt.qb[1] = pt.qb[0]; pt.va[1] = pt.va[0]; pt.vb[1] = pt.vb[0];
    pt.oa[1] = pt.oa[0]; pt.ob[1] = pt.ob[0];
    gemm_pipe<<<dim3(128, 8), 512, 131072, stream>>>(pt, 128, 0, 8, 7);

    // ---- 5) softmax + context -> combined (bf16) ----
    softmax_ctx_img<<<dim3(128, 2), 256, 0, stream>>>(iof_bf, ipf_bf, sc_io, sc_ip, comb_bf);
    softmax_ctx_text<<<dim3(128), 256, 0, stream>>>(tf_bf, sc_to, sc_tp, src_mask, comb_bf);

    // ---- 6) out = combined @ W_out^T + b_out (split-K=8, atomic) ----
    gemm_fin<<<dim3(1, 8, 8), 256, 0, stream>>>(comb_bf, wb[8], b_out, (float*)d_out, 4096, 512);
}

// Round 5
// 320.922 us; speedup vs baseline: 1.0169x; 1.0169x over previous
//
#include <hip/hip_runtime.h>
#include <hip/hip_bf16.h>

typedef __attribute__((ext_vector_type(8))) short bf16x8;
typedef __attribute__((ext_vector_type(4))) float f32x4;

__device__ __forceinline__ uint pack_bf16x2(float a, float b) {
    __hip_bfloat162 p = __float22bfloat162_rn(make_float2(a, b));
    union { __hip_bfloat162 h; uint u; } c; c.h = p; return c.u;
}
__device__ __forceinline__ float bfu(ushort u) { return __uint_as_float(((uint)u) << 16); }

__device__ __forceinline__ float fast_tanh(float x) {
    float e = __expf(2.f * x);
    return 1.f - 2.f * __builtin_amdgcn_rcpf(e + 1.f);
}

__device__ __forceinline__ float wredmax(float v) {
    #pragma unroll
    for (int o = 32; o; o >>= 1) v = fmaxf(v, __shfl_xor(v, o, 64));
    return v;
}
__device__ __forceinline__ float wredsum(float v) {
    #pragma unroll
    for (int o = 32; o; o >>= 1) v += __shfl_xor(v, o, 64);
    return v;
}

__device__ __forceinline__ void gload16(const void* g, void* l) {
    __builtin_amdgcn_global_load_lds(
        (const __attribute__((address_space(1))) void*)g,
        (__attribute__((address_space(3))) void*)l, 16, 0, 0);
}

// ---------------- batched f32 -> bf16 conversion ----------------
struct CvtTab {
    const float* src[16];
    ushort* dst[16];
    unsigned cum[17];
};

__global__ void cvt_all(CvtTab t, unsigned total4) {
    unsigned stride = gridDim.x * blockDim.x;
    for (unsigned i = blockIdx.x * blockDim.x + threadIdx.x; i < total4; i += stride) {
        int j = 0;
        while (i >= t.cum[j + 1]) ++j;
        unsigned off = i - t.cum[j];
        float4 v = reinterpret_cast<const float4*>(t.src[j])[off];
        uint2 o;
        o.x = pack_bf16x2(v.x, v.y);
        o.y = pack_bf16x2(v.z, v.w);
        reinterpret_cast<uint2*>(t.dst[j])[off] = o;
    }
}

// ============ pipelined score GEMM: 512 thr, 256x256 tile, dbuf 128KB LDS ============
// R3-proven body (burst staging at tile top, vmcnt(0) drain per tile) + XCD-chunked
// block remap: chunk = bid&7 pins a contiguous m-region to one XCD so A-tile re-stages
// (one per y) are served by that XCD's L2 instead of L3/HBM.
struct PArgs {
    const ushort* A[2];
    const ushort* Wa[2];
    const ushort* Wb[2];
    const float* qa[2];
    const float* qb[2];
    const float* va[2];
    const float* vb[2];
    float* oa[2];
    float* ob[2];
};

__global__ __launch_bounds__(512, 2) void gemm_pipe(PArgs P, int nmul, int nbadd,
                                                    int bshift, int mchunk,
                                                    int ysub_bits, int br_sh)
{
    extern __shared__ char smem[];
    char* A0 = smem;
    char* A1 = smem + 32768;
    char* W0 = smem + 65536;
    char* W1 = smem + 98304;

    const int tid = threadIdx.x;
    const int lane = tid & 63, wv = tid >> 6;
    const int wr = wv >> 2, wc = wv & 3;
    const int lrow = lane & 15, lk = lane >> 4;

    // ---- XCD-chunked decode: chunk (=XCD) owns mchunk m-tiles x all y; inside,
    // 4m x 4y sub-chunks keep the concurrent L2 working set small.
    const int bid = blockIdx.x;
    const int chunk = bid & 7;
    const int r = bid >> 3;
    const int y_i = r & 3, mm_i = (r >> 2) & 3, sub = r >> 4;
    const int sy = sub & ((1 << ysub_bits) - 1), sm = sub >> ysub_bits;
    const int y = (sy << 2) + y_i;
    const int mt_ext = chunk * mchunk + sm * 4 + mm_i;
    const int br = mt_ext >> br_sh;
    const int m0 = (mt_ext & ((1 << br_sh) - 1)) << 8;
    const int na = y * nmul;
    const int nb = na + nbadd;

    const ushort* A  = P.A[br];
    const ushort* Wa = P.Wa[br];
    const ushort* Wb = P.Wb[br];

    // staging: per half, 512 thr x 16B = 8KB = 64 rows x 128B (linear LDS dest;
    // source chunk pre-swizzled with the same XOR used on ds_read — rule 21)
    const int srow = tid >> 3;
    const int g = (tid & 7) ^ (srow & 7);
    const int sdst = tid * 16;
    const ushort* pA  = A  + (size_t)(m0 + srow) * 1024 + g * 8;
    const ushort* pWa = Wa + (size_t)(na + srow) * 1024 + g * 8;
    const ushort* pWb = Wb + (size_t)(nb + srow) * 1024 + g * 8;

    f32x4 acc[8][4];
    #pragma unroll
    for (int i = 0; i < 8; ++i)
        #pragma unroll
        for (int j = 0; j < 4; ++j) { f32x4 z = {0.f,0.f,0.f,0.f}; acc[i][j] = z; }

    auto stA = [&](int tt, char* dst) {
        #pragma unroll
        for (int j = 0; j < 4; ++j)
            gload16(pA + (size_t)j * 65536 + (size_t)tt * 64, dst + j * 8192 + sdst);
    };
    auto stW = [&](int tt, char* dst) {
        gload16(pWa + (size_t)tt * 64,         dst + sdst);
        gload16(pWa + 65536 + (size_t)tt * 64, dst + 8192 + sdst);
        gload16(pWb + (size_t)tt * 64,         dst + 16384 + sdst);
        gload16(pWb + 65536 + (size_t)tt * 64, dst + 24576 + sdst);
    };
    auto rdA = [&](char* buf, int ks, int mi) -> bf16x8 {
        int row = wr * 128 + mi * 16 + lrow;
        return *(const bf16x8*)(buf + row * 128 + (((ks * 4 + lk) ^ (row & 7)) << 4));
    };
    auto rdB = [&](char* buf, int ks, int ni) -> bf16x8 {
        int row = wc * 64 + ni * 16 + lrow;
        return *(const bf16x8*)(buf + row * 128 + (((ks * 4 + lk) ^ (row & 7)) << 4));
    };

    // prologue: stage tile 0
    stA(0, A0); stW(0, W0);
    asm volatile("s_waitcnt vmcnt(0)" ::: "memory");
    __builtin_amdgcn_s_barrier();

    auto body = [&](int t, char* cA, char* cW, char* nA, char* nW, bool pf) {
        bf16x8 af[4], bfr[4];
        // burst-issue ALL of tile t+1's staging at tile top (max MLP, earliest issue)
        if (pf) { stA(t + 1, nA); stW(t + 1, nW); }
        // ---- phase 0: ks=0, mi 0-3
        #pragma unroll
        for (int ni = 0; ni < 4; ++ni) bfr[ni] = rdB(cW, 0, ni);
        #pragma unroll
        for (int mi = 0; mi < 4; ++mi) af[mi] = rdA(cA, 0, mi);
        __builtin_amdgcn_s_setprio(1);
        #pragma unroll
        for (int mi = 0; mi < 4; ++mi)
            #pragma unroll
            for (int ni = 0; ni < 4; ++ni)
                acc[mi][ni] = __builtin_amdgcn_mfma_f32_16x16x32_bf16(af[mi], bfr[ni], acc[mi][ni], 0, 0, 0);
        __builtin_amdgcn_s_setprio(0);
        // ---- phase 1: ks=0, mi 4-7
        #pragma unroll
        for (int mi = 0; mi < 4; ++mi) af[mi] = rdA(cA, 0, mi + 4);
        __builtin_amdgcn_s_setprio(1);
        #pragma unroll
        for (int mi = 0; mi < 4; ++mi)
            #pragma unroll
            for (int ni = 0; ni < 4; ++ni)
                acc[mi + 4][ni] = __builtin_amdgcn_mfma_f32_16x16x32_bf16(af[mi], bfr[ni], acc[mi + 4][ni], 0, 0, 0);
        __builtin_amdgcn_s_setprio(0);
        // ---- phase 2: ks=1, mi 0-3
        #pragma unroll
        for (int ni = 0; ni < 4; ++ni) bfr[ni] = rdB(cW, 1, ni);
        #pragma unroll
        for (int mi = 0; mi < 4; ++mi) af[mi] = rdA(cA, 1, mi);
        __builtin_amdgcn_s_setprio(1);
        #pragma unroll
        for (int mi = 0; mi < 4; ++mi)
            #pragma unroll
            for (int ni = 0; ni < 4; ++ni)
                acc[mi][ni] = __builtin_amdgcn_mfma_f32_16x16x32_bf16(af[mi], bfr[ni], acc[mi][ni], 0, 0, 0);
        __builtin_amdgcn_s_setprio(0);
        // ---- phase 3: ks=1, mi 4-7
        #pragma unroll
        for (int mi = 0; mi < 4; ++mi) af[mi] = rdA(cA, 1, mi + 4);
        __builtin_amdgcn_s_setprio(1);
        #pragma unroll
        for (int mi = 0; mi < 4; ++mi)
            #pragma unroll
            for (int ni = 0; ni < 4; ++ni)
                acc[mi + 4][ni] = __builtin_amdgcn_mfma_f32_16x16x32_bf16(af[mi], bfr[ni], acc[mi + 4][ni], 0, 0, 0);
        __builtin_amdgcn_s_setprio(0);
        // ---- tile end: drain t+1's loads (full tile of compute to land), barrier
        asm volatile("s_waitcnt vmcnt(0)" ::: "memory");
        __builtin_amdgcn_s_barrier();
    };

    #pragma unroll 1
    for (int tt = 0; tt < 8; ++tt) {
        body(2 * tt,     A0, W0, A1, W1, true);
        body(2 * tt + 1, A1, W1, A0, W0, tt < 7);
    }

    // ---- score epilogue (per-wave side: wc<2 -> a, else -> b) ----
    const float* qsrc = (wc < 2) ? P.qa[br] : P.qb[br];
    const float* vsrc = (wc < 2) ? P.va[br] : P.vb[br];
    float* osrc       = (wc < 2) ? P.oa[br] : P.ob[br];
    const int nbase0 = ((wc < 2) ? na : nb) + (wc & 1) * 64;
    #pragma unroll
    for (int mi = 0; mi < 8; ++mi) {
        int mbase = m0 + wr * 128 + mi * 16;
        int bb = mbase >> bshift;
        const float* qrow = qsrc + (size_t)bb * 1024;
        float part[4] = {0.f, 0.f, 0.f, 0.f};
        #pragma unroll
        for (int ni = 0; ni < 4; ++ni) {
            int nn = nbase0 + ni * 16 + lrow;
            float qn = qrow[nn], vn = vsrc[nn];
            #pragma unroll
            for (int r2 = 0; r2 < 4; ++r2)
                part[r2] += fast_tanh(acc[mi][ni][r2] + qn) * vn;
        }
        #pragma unroll
        for (int off = 1; off < 16; off <<= 1)
            #pragma unroll
            for (int r2 = 0; r2 < 4; ++r2)
                part[r2] += __shfl_xor(part[r2], off, 64);
        if (lrow == 0) {
            #pragma unroll
            for (int r2 = 0; r2 < 4; ++r2)
                atomicAdd(&osrc[mbase + lk * 4 + r2], part[r2]);
        }
    }
}

// ============ fused 4-way q-projection: q = x @ W^T + b  (M=128, single-buffered) ============
struct QArgs {
    const ushort* A[4];
    const ushort* W[4];
    const float* bias[4];
    float* out[4];
};

__global__ __launch_bounds__(256, 2) void gemm_q(QArgs Q)
{
    __shared__ char smemq[32768];
    char* As = smemq;
    char* Ws = smemq + 16384;

    const int tid = threadIdx.x;
    const int lane = tid & 63, wv = tid >> 6, wr = wv >> 1, wc = wv & 1;
    const int lrow = lane & 15, lk = lane >> 4;
    const int n0 = blockIdx.y << 7;

    const ushort* A = Q.A[blockIdx.x];
    const ushort* W = Q.W[blockIdx.x];

    f32x4 acc[4][4];
    #pragma unroll
    for (int i = 0; i < 4; ++i)
        #pragma unroll
        for (int j = 0; j < 4; ++j) { f32x4 z = {0.f,0.f,0.f,0.f}; acc[i][j] = z; }

    const int srow = tid >> 3;
    const int g = (tid & 7) ^ (srow & 7);
    const ushort* pA = A + (size_t)srow * 1024 + g * 8;
    const ushort* pW = W + (size_t)(n0 + srow) * 1024 + g * 8;

    for (int t = 0; t < 16; ++t) {
        #pragma unroll
        for (int j = 0; j < 4; ++j)
            gload16(pA + (size_t)j * 32768 + (size_t)t * 64, As + j * 4096 + tid * 16);
        #pragma unroll
        for (int j = 0; j < 4; ++j)
            gload16(pW + (size_t)j * 32768 + (size_t)t * 64, Ws + j * 4096 + tid * 16);
        __syncthreads();
        #pragma unroll
        for (int ks = 0; ks < 2; ++ks) {
            bf16x8 af[4], bfr[4];
            const int q = ks * 4 + lk;
            #pragma unroll
            for (int mi = 0; mi < 4; ++mi) {
                int row = wr * 64 + mi * 16 + lrow;
                af[mi] = *(const bf16x8*)(As + row * 128 + ((q ^ (row & 7)) << 4));
            }
            #pragma unroll
            for (int ni = 0; ni < 4; ++ni) {
                int row = wc * 64 + ni * 16 + lrow;
                bfr[ni] = *(const bf16x8*)(Ws + row * 128 + ((q ^ (row & 7)) << 4));
            }
            #pragma unroll
            for (int mi = 0; mi < 4; ++mi)
                #pragma unroll
                for (int ni = 0; ni < 4; ++ni)
                    acc[mi][ni] = __builtin_amdgcn_mfma_f32_16x16x32_bf16(af[mi], bfr[ni], acc[mi][ni], 0, 0, 0);
        }
        __syncthreads();
    }

    float* out = Q.out[blockIdx.x];
    const float* bias = Q.bias[blockIdx.x];
    #pragma unroll
    for (int mi = 0; mi < 4; ++mi) {
        int mrow0 = wr * 64 + mi * 16 + lk * 4;
        #pragma unroll
        for (int ni = 0; ni < 4; ++ni) {
            int n = n0 + wc * 64 + ni * 16 + lrow;
            float bv = bias[n];
            #pragma unroll
            for (int r = 0; r < 4; ++r)
                out[(size_t)(mrow0 + r) * 1024 + n] = acc[mi][ni][r] + bv;
        }
    }
}

// ============ final GEMM (split-K, atomic): out += combined @ W_out^T (+bias at z==0) ============
__global__ __launch_bounds__(256, 2) void gemm_fin(
    const ushort* A, const ushort* W, const float* bias, float* out, int K, int kchunk)
{
    __shared__ char smemf[32768];
    char* As = smemf;
    char* Ws = smemf + 16384;

    const int tid = threadIdx.x;
    const int lane = tid & 63, wv = tid >> 6, wr = wv >> 1, wc = wv & 1;
    const int lrow = lane & 15, lk = lane >> 4;
    const int n0 = blockIdx.y << 7;
    const int nkt = kchunk >> 6;
    const int ktbase = blockIdx.z * nkt;

    f32x4 acc[4][4];
    #pragma unroll
    for (int i = 0; i < 4; ++i)
        #pragma unroll
        for (int j = 0; j < 4; ++j) { f32x4 z = {0.f,0.f,0.f,0.f}; acc[i][j] = z; }

    const int srow = tid >> 3;
    const int g = (tid & 7) ^ (srow & 7);
    const ushort* pA = A + (size_t)srow * K + ktbase * 64 + g * 8;
    const ushort* pW = W + (size_t)(n0 + srow) * K + ktbase * 64 + g * 8;

    for (int t = 0; t < nkt; ++t) {
        #pragma unroll
        for (int j = 0; j < 4; ++j)
            gload16(pA + (size_t)j * 32 * K + (size_t)t * 64, As + j * 4096 + tid * 16);
        #pragma unroll
        for (int j = 0; j < 4; ++j)
            gload16(pW + (size_t)j * 32 * K + (size_t)t * 64, Ws + j * 4096 + tid * 16);
        __syncthreads();
        #pragma unroll
        for (int ks = 0; ks < 2; ++ks) {
            bf16x8 af[4], bfr[4];
            const int q = ks * 4 + lk;
            #pragma unroll
            for (int mi = 0; mi < 4; ++mi) {
                int row = wr * 64 + mi * 16 + lrow;
                af[mi] = *(const bf16x8*)(As + row * 128 + ((q ^ (row & 7)) << 4));
            }
            #pragma unroll
            for (int ni = 0; ni < 4; ++ni) {
                int row = wc * 64 + ni * 16 + lrow;
                bfr[ni] = *(const bf16x8*)(Ws + row * 128 + ((q ^ (row & 7)) << 4));
            }
            #pragma unroll
            for (int mi = 0; mi < 4; ++mi)
                #pragma unroll
                for (int ni = 0; ni < 4; ++ni)
                    acc[mi][ni] = __builtin_amdgcn_mfma_f32_16x16x32_bf16(af[mi], bfr[ni], acc[mi][ni], 0, 0, 0);
        }
        __syncthreads();
    }

    #pragma unroll
    for (int mi = 0; mi < 4; ++mi) {
        int mrow0 = wr * 64 + mi * 16 + lk * 4;
        #pragma unroll
        for (int ni = 0; ni < 4; ++ni) {
            int n = n0 + wc * 64 + ni * 16 + lrow;
            float bv = (blockIdx.z == 0) ? bias[n] : 0.f;
            #pragma unroll
            for (int r = 0; r < 4; ++r)
                atomicAdd(&out[(size_t)(mrow0 + r) * 1024 + n], acc[mi][ni][r] + bv);
        }
    }
}

// ---------------- softmax + context, image branches ----------------
__global__ void softmax_ctx_img(const ushort* __restrict__ iof, const ushort* __restrict__ ipf,
                                const float* __restrict__ sc_io, const float* __restrict__ sc_ip,
                                ushort* __restrict__ combined)
{
    int b = blockIdx.x, br = blockIdx.y;
    const ushort* A  = br ? ipf : iof;
    const float* sc  = br ? sc_ip : sc_io;
    __shared__ float dist[64];
    int tid = threadIdx.x;
    if (tid < 64) {
        float s  = sc[b * 64 + tid];
        float mx = wredmax(s);
        float e  = __expf(s - mx);
        float sm = wredsum(e);
        dist[tid] = e / sm;
    }
    __syncthreads();
    int d0 = tid * 4;
    float a0 = 0, a1 = 0, a2 = 0, a3 = 0;
    const ushort* base = A + (size_t)b * 64 * 1024 + d0;
    #pragma unroll 4
    for (int n = 0; n < 64; ++n) {
        float w = dist[n];
        ushort4 t = *(const ushort4*)(base + (size_t)n * 1024);
        a0 += w * bfu(t.x); a1 += w * bfu(t.y); a2 += w * bfu(t.z); a3 += w * bfu(t.w);
    }
    uint2 o;
    o.x = pack_bf16x2(a0, a1);
    o.y = pack_bf16x2(a2, a3);
    *(uint2*)(combined + (size_t)b * 4096 + br * 1024 + d0) = o;
}

// ---------------- masked softmax + context, text branches ----------------
__global__ void softmax_ctx_text(const ushort* __restrict__ tf,
                                 const float* __restrict__ sc_to, const float* __restrict__ sc_tp,
                                 const float* __restrict__ mask, ushort* __restrict__ combined)
{
    int b = blockIdx.x;
    __shared__ float d3[256], d4[256], red[8];
    int tid = threadIdx.x, lane = tid & 63, wv = tid >> 6;
    float s3 = sc_to[b * 256 + tid], s4 = sc_tp[b * 256 + tid], m = mask[b * 256 + tid];
    float m3 = wredmax(s3), m4 = wredmax(s4);
    if (lane == 0) { red[wv] = m3; red[4 + wv] = m4; }
    __syncthreads();
    m3 = fmaxf(fmaxf(red[0], red[1]), fmaxf(red[2], red[3]));
    m4 = fmaxf(fmaxf(red[4], red[5]), fmaxf(red[6], red[7]));
    float e3 = __expf(s3 - m3) * m, e4 = __expf(s4 - m4) * m;
    float t3 = wredsum(e3), t4 = wredsum(e4);
    __syncthreads();
    if (lane == 0) { red[wv] = t3; red[4 + wv] = t4; }
    __syncthreads();
    t3 = red[0] + red[1] + red[2] + red[3];
    t4 = red[4] + red[5] + red[6] + red[7];
    d3[tid] = e3 / t3; d4[tid] = e4 / t4;
    __syncthreads();
    int d0 = tid * 4;
    float a0 = 0, a1 = 0, a2 = 0, a3 = 0, c0 = 0, c1 = 0, c2 = 0, c3 = 0;
    const ushort* base = tf + (size_t)b * 256 * 1024 + d0;
    #pragma unroll 4
    for (int l = 0; l < 256; ++l) {
        float w3 = d3[l], w4 = d4[l];
        ushort4 t = *(const ushort4*)(base + (size_t)l * 1024);
        float f0 = bfu(t.x), f1 = bfu(t.y), f2 = bfu(t.z), f3 = bfu(t.w);
        a0 += w3 * f0; a1 += w3 * f1; a2 += w3 * f2; a3 += w3 * f3;
        c0 += w4 * f0; c1 += w4 * f1; c2 += w4 * f2; c3 += w4 * f3;
    }
    uint2 o;
    o.x = pack_bf16x2(a0, a1); o.y = pack_bf16x2(a2, a3);
    *(uint2*)(combined + (size_t)b * 4096 + 2048 + d0) = o;
    o.x = pack_bf16x2(c0, c1); o.y = pack_bf16x2(c2, c3);
    *(uint2*)(combined + (size_t)b * 4096 + 3072 + d0) = o;
}

extern "C" void kernel_launch(void* const* d_in, const int* in_sizes, int n_in,
                              void* d_out, int out_size, void* d_ws, size_t ws_size,
                              hipStream_t stream) {
    const float* text_feat        = (const float*)d_in[0];
    const float* text_feats       = (const float*)d_in[1];
    const float* img_object_feat  = (const float*)d_in[2];
    const float* img_object_feats = (const float*)d_in[3];
    const float* img_place_feat   = (const float*)d_in[4];
    const float* img_place_feats  = (const float*)d_in[5];
    const float* src_mask         = (const float*)d_in[6];
    const float* v_to  = (const float*)d_in[7];
    const float* v_tp  = (const float*)d_in[8];
    const float* v_io  = (const float*)d_in[9];
    const float* v_ip  = (const float*)d_in[10];
    const float* Wsrc[9] = {
        (const float*)d_in[11],  // W_t2o
        (const float*)d_in[12],  // W_t2p
        (const float*)d_in[13],  // W_o2t
        (const float*)d_in[14],  // W_p2t
        (const float*)d_in[15],  // W_oo
        (const float*)d_in[17],  // W_pp
        (const float*)d_in[19],  // W_tot
        (const float*)d_in[21],  // W_tpt
        (const float*)d_in[23],  // W_out
    };
    const float* b_oo  = (const float*)d_in[16];
    const float* b_pp  = (const float*)d_in[18];
    const float* b_tot = (const float*)d_in[20];
    const float* b_tpt = (const float*)d_in[22];
    const float* b_out = (const float*)d_in[24];

    // ---- workspace layout ----
    char* p = (char*)d_ws;
    auto alloc = [&](size_t bytes) { char* r = p; p += (bytes + 255) & ~(size_t)255; return r; };
    ushort* wb[9];
    for (int i = 0; i < 8; ++i) wb[i] = (ushort*)alloc((size_t)1024 * 1024 * 2);
    wb[8] = (ushort*)alloc((size_t)1024 * 4096 * 2);
    ushort* tf_bf   = (ushort*)alloc((size_t)32768 * 1024 * 2);
    ushort* iof_bf  = (ushort*)alloc((size_t)8192 * 1024 * 2);
    ushort* ipf_bf  = (ushort*)alloc((size_t)8192 * 1024 * 2);
    ushort* tfq_bf  = (ushort*)alloc((size_t)128 * 1024 * 2);
    ushort* iofq_bf = (ushort*)alloc((size_t)128 * 1024 * 2);
    ushort* ipfq_bf = (ushort*)alloc((size_t)128 * 1024 * 2);
    float* q_tot = (float*)alloc((size_t)128 * 1024 * 4);
    float* q_tpt = (float*)alloc((size_t)128 * 1024 * 4);
    float* q_oo  = (float*)alloc((size_t)128 * 1024 * 4);
    float* q_pp  = (float*)alloc((size_t)128 * 1024 * 4);
    float* scores = (float*)alloc((size_t)(8192 * 2 + 32768 * 2) * 4);
    float* sc_io = scores, *sc_ip = scores + 8192, *sc_to = scores + 16384, *sc_tp = scores + 49152;
    ushort* comb_bf = (ushort*)alloc((size_t)128 * 4096 * 2);

    // ---- 1) batched f32->bf16 conversion ----
    CvtTab tab;
    unsigned n4[15];
    const float* srcs[15];
    ushort* dsts[15];
    for (int i = 0; i < 8; ++i) { srcs[i] = Wsrc[i]; dsts[i] = wb[i]; n4[i] = 262144; }
    srcs[8]  = Wsrc[8];          dsts[8]  = wb[8];   n4[8]  = 1048576;
    srcs[9]  = text_feats;       dsts[9]  = tf_bf;   n4[9]  = 8388608;
    srcs[10] = img_object_feats; dsts[10] = iof_bf;  n4[10] = 2097152;
    srcs[11] = img_place_feats;  dsts[11] = ipf_bf;  n4[11] = 2097152;
    srcs[12] = text_feat;        dsts[12] = tfq_bf;  n4[12] = 32768;
    srcs[13] = img_object_feat;  dsts[13] = iofq_bf; n4[13] = 32768;
    srcs[14] = img_place_feat;   dsts[14] = ipfq_bf; n4[14] = 32768;
    unsigned cum = 0;
    for (int i = 0; i < 15; ++i) {
        tab.src[i] = srcs[i]; tab.dst[i] = dsts[i]; tab.cum[i] = cum; cum += n4[i];
    }
    tab.src[15] = nullptr; tab.dst[15] = nullptr; tab.cum[15] = cum; tab.cum[16] = cum;
    cvt_all<<<4096, 256, 0, stream>>>(tab, cum);

    // ---- 2) zero atomic targets ----
    hipMemsetAsync(scores, 0, (size_t)(8192 * 2 + 32768 * 2) * 4, stream);
    hipMemsetAsync(d_out, 0, (size_t)128 * 1024 * 4, stream);

    // ---- 3) fused q projections ----
    QArgs qa;
    qa.A[0] = tfq_bf;  qa.W[0] = wb[6]; qa.bias[0] = b_tot; qa.out[0] = q_tot;
    qa.A[1] = tfq_bf;  qa.W[1] = wb[7]; qa.bias[1] = b_tpt; qa.out[1] = q_tpt;
    qa.A[2] = iofq_bf; qa.W[2] = wb[4]; qa.bias[2] = b_oo;  qa.out[2] = q_oo;
    qa.A[3] = ipfq_bf; qa.W[3] = wb[5]; qa.bias[3] = b_pp;  qa.out[3] = q_pp;
    gemm_q<<<dim3(4, 8), 256, 0, stream>>>(qa);

    // ---- 4) score GEMMs (XCD-chunked) ----
    // img: 256 blocks = 8 chunks x (8 m_ext x 4 y); br = mt_ext>>5
    PArgs pi;
    pi.A[0] = iof_bf;  pi.Wa[0] = wb[2]; pi.Wb[0] = wb[2];
    pi.qa[0] = q_tot;  pi.qb[0] = q_tot; pi.va[0] = v_to; pi.vb[0] = v_to;
    pi.oa[0] = sc_io;  pi.ob[0] = sc_io;
    pi.A[1] = ipf_bf;  pi.Wa[1] = wb[3]; pi.Wb[1] = wb[3];
    pi.qa[1] = q_tpt;  pi.qb[1] = q_tpt; pi.va[1] = v_tp; pi.vb[1] = v_tp;
    pi.oa[1] = sc_ip;  pi.ob[1] = sc_ip;
    gemm_pipe<<<dim3(256), 512, 131072, stream>>>(pi, 256, 128, 6, 8, 0, 5);

    // text: 1024 blocks = 8 chunks x (16 m x 8 y); dual-W, br always 0
    PArgs pt;
    pt.A[0] = tf_bf;   pt.Wa[0] = wb[0]; pt.Wb[0] = wb[1];
    pt.qa[0] = q_oo;   pt.qb[0] = q_pp;  pt.va[0] = v_io; pt.vb[0] = v_ip;
    pt.oa[0] = sc_to;  pt.ob[0] = sc_tp;
    pt.A[1] = pt.A[0]; pt.Wa[1] = pt.Wa[0]; pt.Wb[1] = pt.Wb[0];
    pt.qa[1] = pt.qa[0]; pt.qb[1] = pt.qb[0]; pt.va[1] = pt.va[0]; pt.vb[1] = pt.vb[0];
    pt.oa[1] = pt.oa[0]; pt.ob[1] = pt.ob[0];
    gemm_pipe<<<dim3(1024), 512, 131072, stream>>>(pt, 128, 0, 8, 16, 1, 30);

    // ---- 5) softmax + context -> combined (bf16) ----
    softmax_ctx_img<<<dim3(128, 2), 256, 0, stream>>>(iof_bf, ipf_bf, sc_io, sc_ip, comb_bf);
    softmax_ctx_text<<<dim3(128), 256, 0, stream>>>(tf_bf, sc_to, sc_tp, src_mask, comb_bf);

    // ---- 6) out = combined @ W_out^T + b_out (split-K=8, atomic) ----
    gemm_fin<<<dim3(1, 8, 8), 256, 0, stream>>>(comb_bf, wb[8], b_out, (float*)d_out, 4096, 512);
}